// Round 9
// baseline (769.047 us; speedup 1.0000x reference)
//
#include <hip/hip_runtime.h>
#include <math.h>

#define NLAYERS 6
#define HD 256
#define NS 32
#define NCLS 50
#define BB 16
#define LL 2048
#define TT 64
#define CC 32

typedef __attribute__((ext_vector_type(8))) short bf16x8;
typedef __attribute__((ext_vector_type(4))) float f32x4;

// ---- static device workspaces ----
__device__ __attribute__((aligned(16))) float g_x [8388608];   // [B][L][H] residual stream (fp32)
__device__ __attribute__((aligned(16))) float g_Vt[6389760];   // [l][h][n][65][2] : w^t, t=0..64
__device__ __attribute__((aligned(16))) float g_Kt[98304];     // [l][h][64] kernel taps
__device__ __attribute__((aligned(16))) float g_E0[98304];     // [l][h][n][2] : C*dB
__device__ __attribute__((aligned(16))) float g_pp[65536];     // [B][16][H] pool partials
__device__ __attribute__((aligned(16))) unsigned short g_zbh[8388608]; // z bf16 [B][H][L]
__device__ __attribute__((aligned(16))) unsigned short g_Mt [12582912];// [l][h][t=64][k=128] bf16 (TK;TC)^T, D folded
__device__ __attribute__((aligned(16))) unsigned short g_TAt[6291456]; // [l][h][p=64][t=64] bf16 TA^T
__device__ __attribute__((aligned(16))) unsigned short g_ybh[8388608]; // y bf16 [B][H][L]
__device__ __attribute__((aligned(16))) unsigned short g_Wt [786432];  // Wt bf16 [l][n=512][k=256]
__device__ __attribute__((aligned(16))) unsigned short g_xb [4194304]; // x_in bf16 [32768][128]
__device__ __attribute__((aligned(16))) unsigned short g_Wint[32768];  // W_in^T bf16 [n=256][k=128]

__device__ __forceinline__ float sigf(float x) { return 1.0f / (1.0f + __expf(-x)); }
__device__ __forceinline__ float geluf(float x) {
  float t = 0.7978845608028654f * (x + 0.044715f * x * x * x);
  float e = __expf(2.0f * t);
  float th = 1.0f - 2.0f / (e + 1.0f);
  return 0.5f * x * (1.0f + th);
}
__device__ __forceinline__ unsigned short f2bf(float f) {
  unsigned u = __float_as_uint(f);
  unsigned r = (u + 0x7FFFu + ((u >> 16) & 1u)) >> 16;
  return (unsigned short)r;
}
__device__ __forceinline__ float bf2f(unsigned short u) {
  return __uint_as_float(((unsigned)u) << 16);
}

// ---------- precompute: w, E0 = C*dB, power table w^t ----------
__global__ void k_precomp(const float* __restrict__ log_dt,
                          const float* __restrict__ A_re, const float* __restrict__ A_im,
                          const float* __restrict__ B_re, const float* __restrict__ B_im,
                          const float* __restrict__ C_re, const float* __restrict__ C_im) {
  int id = blockIdx.x * 256 + threadIdx.x;
  if (id >= NLAYERS * HD * NS) return;
  int h = (id / NS) % HD;
  int i = id / (NS * HD);
  float dt = expf(log_dt[i * HD + h]);
  float ar = A_re[id], ai = A_im[id];
  float dr = dt * ar, di = dt * ai;
  float er = expf(dr);
  float wr = er * cosf(di), wi = er * sinf(di);
  float inv = 1.0f / (ar * ar + ai * ai);
  float mr = wr - 1.0f, mi = wi;
  float qr = (mr * ar + mi * ai) * inv;
  float qi = (mi * ar - mr * ai) * inv;
  float br = B_re[id], bi = B_im[id];
  float dbr = br * qr - bi * qi, dbi = br * qi + bi * qr;
  float cr = C_re[id], ci = C_im[id];
  g_E0[id * 2 + 0] = cr * dbr - ci * dbi;
  g_E0[id * 2 + 1] = cr * dbi + ci * dbr;
  float pr = 1.0f, pi = 0.0f;
  long base = (long)id * 65;
  for (int t = 0; t <= 64; ++t) {
    g_Vt[(base + t) * 2 + 0] = pr;
    g_Vt[(base + t) * 2 + 1] = pi;
    float nr = pr * wr - pi * wi;
    pi = pr * wi + pi * wr;
    pr = nr;
  }
}

__global__ void k_precompK() {
  int id = blockIdx.x * 256 + threadIdx.x;
  if (id >= NLAYERS * HD * TT) return;
  int t = id % TT;
  int lh = id / TT;
  float acc = 0.f;
  const float* e = g_E0 + (long)lh * NS * 2;
  const float* v = g_Vt + ((long)lh * NS * 65 + t) * 2;
  for (int n = 0; n < NS; ++n)
    acc += e[n * 2] * v[n * 130] - e[n * 2 + 1] * v[n * 130 + 1];
  g_Kt[id] = 2.0f * acc;
}

// Mt[l][h][t][k] bf16: k<64 -> TK[s=k][t] (+D at k==t); k>=64 -> TC[p=k-64][t]
__global__ void k_precompM(const float* __restrict__ Dd) {
  int id = blockIdx.x * 256 + threadIdx.x;     // 12582912
  int k = id & 127;
  int t = (id >> 7) & 63;
  int lh = id >> 13;
  float v;
  if (k < 64) {
    v = (t >= k) ? g_Kt[(long)lh * 64 + (t - k)] : 0.f;
    if (k == t) v += Dd[lh];
  } else {
    int p = k - 64, n = p >> 1;
    const float2 w = ((const float2*)g_Vt)[((long)lh * NS + n) * 65 + (t + 1)];
    v = (p & 1) ? (-2.f * w.y) : (2.f * w.x);
  }
  g_Mt[id] = f2bf(v);
}

// TAt[l][h][p][t] = TA[t][p] bf16
__global__ void k_precompA2() {
  int id = blockIdx.x * 256 + threadIdx.x;     // 6291456
  int t = id & 63;
  int p = (id >> 6) & 63;
  int lh = id >> 12;
  int n = p >> 1;
  const float2 w = ((const float2*)g_Vt)[((long)lh * NS + n) * 65 + (63 - t)];
  g_TAt[id] = f2bf((p & 1) ? w.y : w.x);
}

// ---------- W_out -> Wt bf16 [l][n][k] ----------
__global__ __launch_bounds__(256) void k_prepW(const float* __restrict__ W_out) {
  __shared__ float T[32][33];
  int bid = blockIdx.x;
  int nt = bid & 15, kt = (bid >> 4) & 7, l = bid >> 7;
  int t = threadIdx.x;
  int tr = t >> 3, tc = t & 7;
  const float* src = W_out + (long)l * 131072 + (long)(kt * 32) * 512 + nt * 32;
  float4 v = *(const float4*)(src + (long)tr * 512 + tc * 4);
  T[tr][tc * 4 + 0] = v.x; T[tr][tc * 4 + 1] = v.y;
  T[tr][tc * 4 + 2] = v.z; T[tr][tc * 4 + 3] = v.w;
  __syncthreads();
  ushort4 o;
  o.x = f2bf(T[tc * 4 + 0][tr]); o.y = f2bf(T[tc * 4 + 1][tr]);
  o.z = f2bf(T[tc * 4 + 2][tr]); o.w = f2bf(T[tc * 4 + 3][tr]);
  *(ushort4*)(g_Wt + ((long)l * 512 + nt * 32 + tr) * 256 + kt * 32 + tc * 4) = o;
}

// ---------- W_in [k=128][n=256] -> Wint bf16 [n][k] ----------
__global__ void k_prepWin(const float* __restrict__ W_in) {
  int k = blockIdx.x, n = threadIdx.x;
  g_Wint[n * 128 + k] = f2bf(W_in[k * 256 + n]);
}

// ---------- x_in fp32 -> bf16 ----------
__global__ void k_castin(const float* __restrict__ xin) {
  long base = ((long)blockIdx.x * 256 + threadIdx.x) * 8;
  float4 v0 = *(const float4*)(xin + base);
  float4 v1 = *(const float4*)(xin + base + 4);
  union { unsigned short u[8]; ulonglong2 v; } pk;
  pk.u[0] = f2bf(v0.x); pk.u[1] = f2bf(v0.y); pk.u[2] = f2bf(v0.z); pk.u[3] = f2bf(v0.w);
  pk.u[4] = f2bf(v1.x); pk.u[5] = f2bf(v1.y); pk.u[6] = f2bf(v1.z); pk.u[7] = f2bf(v1.w);
  *(ulonglong2*)(g_xb + base) = pk.v;
}

// ---------- input GEMM (bf16 MFMA): g_x[32768,256] = xb[32768,128]*Wint^T + b ----------
__global__ __launch_bounds__(256) void k_gemmin(const float* __restrict__ bias) {
  __shared__ __attribute__((aligned(16))) unsigned short As[128 * 32];
  __shared__ __attribute__((aligned(16))) unsigned short Bs[256 * 32];
  const int tid = threadIdx.x;
  const int wave = tid >> 6, lane = tid & 63;
  const int m0 = blockIdx.x * 128;
  const int wm = wave & 1, wn = wave >> 1;
  const int n15 = lane & 15, kg = lane >> 4, q2 = kg * 8;
  f32x4 acc[4][8];
  #pragma unroll
  for (int a = 0; a < 4; ++a)
    #pragma unroll
    for (int b2 = 0; b2 < 8; ++b2) acc[a][b2] = (f32x4){0.f, 0.f, 0.f, 0.f};
  for (int k0 = 0; k0 < 128; k0 += 32) {
    __syncthreads();
    #pragma unroll
    for (int it = 0; it < 2; ++it) {
      int slot = it * 256 + wave * 64 + lane;
      int m = slot >> 2, ko = (slot & 3) * 8;
      __builtin_amdgcn_global_load_lds(
        (const __attribute__((address_space(1))) unsigned int*)(g_xb + (long)(m0 + m) * 128 + k0 + ko),
        (__attribute__((address_space(3))) unsigned int*)(As + (it * 256 + wave * 64) * 8),
        16, 0, 0);
    }
    #pragma unroll
    for (int it = 0; it < 4; ++it) {
      int slot = it * 256 + wave * 64 + lane;
      int n = slot >> 2, ko = (slot & 3) * 8;
      __builtin_amdgcn_global_load_lds(
        (const __attribute__((address_space(1))) unsigned int*)(g_Wint + (long)n * 128 + k0 + ko),
        (__attribute__((address_space(3))) unsigned int*)(Bs + (it * 256 + wave * 64) * 8),
        16, 0, 0);
    }
    __syncthreads();
    bf16x8 af[4], bn[8];
    #pragma unroll
    for (int mt = 0; mt < 4; ++mt)
      af[mt] = *(const bf16x8*)&As[(wm * 64 + mt * 16 + n15) * 32 + q2];
    #pragma unroll
    for (int j = 0; j < 8; ++j)
      bn[j] = *(const bf16x8*)&Bs[(wn * 128 + j * 16 + n15) * 32 + q2];
    #pragma unroll
    for (int mt = 0; mt < 4; ++mt)
      #pragma unroll
      for (int j = 0; j < 8; ++j)
        acc[mt][j] = __builtin_amdgcn_mfma_f32_16x16x32_bf16(af[mt], bn[j], acc[mt][j], 0, 0, 0);
  }
  #pragma unroll
  for (int j = 0; j < 8; ++j) {
    int col = wn * 128 + j * 16 + n15;
    float bb = bias[col];
    #pragma unroll
    for (int mt = 0; mt < 4; ++mt)
      #pragma unroll
      for (int r = 0; r < 4; ++r) {
        int row = m0 + wm * 64 + mt * 16 + kg * 4 + r;
        g_x[(long)row * 256 + col] = acc[mt][j][r] + bb;
      }
  }
}

// ---------- LayerNorm over H -> z bf16 [B][H][L]; only for layer 0 ----------
__global__ __launch_bounds__(256) void k_ln(const float* __restrict__ gam,
                                            const float* __restrict__ bet) {
  __shared__ unsigned short S[32 * 264];
  const int bid = blockIdx.x;                  // 1024
  const int b = bid >> 6, l0 = (bid & 63) << 5;
  const int tid = threadIdx.x, w = tid >> 6, lane = tid & 63;
  float4 gv = *(const float4*)(gam + lane * 4);
  float4 bv = *(const float4*)(bet + lane * 4);
  for (int r = 0; r < 8; ++r) {
    int ll = w * 8 + r;
    float4 v = *(const float4*)(g_x + ((long)(b * LL + l0 + ll)) * HD + lane * 4);
    float s1 = v.x + v.y + v.z + v.w;
    float s2 = v.x * v.x + v.y * v.y + v.z * v.z + v.w * v.w;
    #pragma unroll
    for (int off = 32; off; off >>= 1) { s1 += __shfl_xor(s1, off); s2 += __shfl_xor(s2, off); }
    float mu = s1 * (1.0f / HD);
    float rs = rsqrtf(s2 * (1.0f / HD) - mu * mu + 1e-5f);
    ushort4 o;
    o.x = f2bf((v.x - mu) * rs * gv.x + bv.x);
    o.y = f2bf((v.y - mu) * rs * gv.y + bv.y);
    o.z = f2bf((v.z - mu) * rs * gv.z + bv.z);
    o.w = f2bf((v.w - mu) * rs * gv.w + bv.w);
    *(ushort4*)&S[ll * 264 + lane * 4] = o;
  }
  __syncthreads();
  unsigned short* zp = g_zbh + ((long)(b * HD + tid)) * LL + l0;
  #pragma unroll
  for (int seg = 0; seg < 4; ++seg) {
    union { unsigned short u[8]; ulonglong2 v; } pk;
    #pragma unroll
    for (int i = 0; i < 8; ++i) pk.u[i] = S[(seg * 8 + i) * 264 + tid];
    *(ulonglong2*)(zp + seg * 8) = pk.v;
  }
}

// ---------- fused SSM: phaseA (MFMA) + chunk scan + phaseC (MFMA), one block per (b,h) ----------
__global__ __launch_bounds__(256) void k_ssm(int layer) {
  __shared__ __attribute__((aligned(16))) unsigned short Zs[32 * 72];   // z [c][t]
  __shared__ __attribute__((aligned(16))) unsigned short Ts[64 * 72];   // TA^T [p][t] | Ss fp32 [c][p] pitch 68
  __shared__ __attribute__((aligned(16))) unsigned short Ms[64 * 136];  // Mt [t][k]
  __shared__ __attribute__((aligned(16))) unsigned short Gs[32 * 72];   // G [c][p]
  float* Ss = (float*)Ts;
  const int tid = threadIdx.x, wave = tid >> 6, lane = tid & 63;
  const int h = blockIdx.x & 255, b = blockIdx.x >> 8;
  const long lh = (long)layer * HD + h;
  {
    int c = tid >> 3, off = (tid & 7) * 8;
    *(ulonglong2*)&Zs[c * 72 + off] =
        *(const ulonglong2*)(g_zbh + ((long)(b * HD + h)) * LL + c * 64 + off);
  }
  const unsigned short* Tg = g_TAt + lh * 4096;
  #pragma unroll
  for (int i = 0; i < 2; ++i) {
    int seg = tid + i * 256;
    int row = seg >> 3, sc = (seg & 7) * 8;
    *(ulonglong2*)&Ts[row * 72 + sc] = *(const ulonglong2*)(Tg + row * 64 + sc);
  }
  const unsigned short* Mg = g_Mt + lh * 8192;
  #pragma unroll
  for (int i = 0; i < 4; ++i) {
    int seg = tid + i * 256;
    int row = seg >> 4, sc = (seg & 15) * 8;
    *(ulonglong2*)&Ms[row * 136 + sc] = *(const ulonglong2*)(Mg + row * 128 + sc);
  }
  __syncthreads();
  const int n15 = lane & 15, kg = lane >> 4;
  const int mt = wave & 1;
  const int jb = (wave >> 1) * 2;
  const int c = mt * 16 + n15;
  {
    bf16x8 a0 = *(const bf16x8*)&Zs[c * 72 + kg * 8];
    bf16x8 a1 = *(const bf16x8*)&Zs[c * 72 + 32 + kg * 8];
    bf16x8 tb0[2], tb1[2];
    #pragma unroll
    for (int jj = 0; jj < 2; ++jj) {
      int j = jb + jj;
      tb0[jj] = *(const bf16x8*)&Ts[(j * 16 + n15) * 72 + kg * 8];
      tb1[jj] = *(const bf16x8*)&Ts[(j * 16 + n15) * 72 + 32 + kg * 8];
    }
    f32x4 accA[2];
    #pragma unroll
    for (int jj = 0; jj < 2; ++jj) {
      accA[jj] = (f32x4){0.f, 0.f, 0.f, 0.f};
      accA[jj] = __builtin_amdgcn_mfma_f32_16x16x32_bf16(a0, tb0[jj], accA[jj], 0, 0, 0);
      accA[jj] = __builtin_amdgcn_mfma_f32_16x16x32_bf16(a1, tb1[jj], accA[jj], 0, 0, 0);
    }
    __syncthreads();                     // all Ts reads done; safe to alias as Ss
    #pragma unroll
    for (int jj = 0; jj < 2; ++jj) {
      int j = jb + jj;
      #pragma unroll
      for (int r = 0; r < 4; ++r)
        Ss[(mt * 16 + kg * 4 + r) * 68 + j * 16 + n15] = accA[jj][r];
    }
  }
  __syncthreads();
  if (wave == 0 && lane < 32) {
    int n = lane;
    long vb = (lh * NS + n) * 65;
    float wtr = g_Vt[vb * 2 + 128], wti = g_Vt[vb * 2 + 129];
    float e0r = g_E0[(lh * NS + n) * 2], e0i = g_E0[(lh * NS + n) * 2 + 1];
    float sr = 0.f, si = 0.f;
    for (int cc = 0; cc < CC; ++cc) {
      float er = Ss[cc * 68 + 2 * n], ei = Ss[cc * 68 + 2 * n + 1];
      Gs[cc * 72 + 2 * n]     = f2bf(e0r * sr - e0i * si);
      Gs[cc * 72 + 2 * n + 1] = f2bf(e0r * si + e0i * sr);
      float nr = er + wtr * sr - wti * si;
      si      = ei + wtr * si + wti * sr;
      sr = nr;
    }
  }
  __syncthreads();
  {
    bf16x8 a0 = *(const bf16x8*)&Zs[c * 72 + kg * 8];
    bf16x8 a1 = *(const bf16x8*)&Zs[c * 72 + 32 + kg * 8];
    bf16x8 a2 = *(const bf16x8*)&Gs[c * 72 + kg * 8];
    bf16x8 a3 = *(const bf16x8*)&Gs[c * 72 + 32 + kg * 8];
    unsigned short* yrow = g_ybh + ((long)(b * HD + h)) * LL;
    #pragma unroll
    for (int jj = 0; jj < 2; ++jj) {
      int j = jb + jj;
      const unsigned short* mrow = &Ms[(j * 16 + n15) * 136];
      bf16x8 b0 = *(const bf16x8*)&mrow[kg * 8];
      bf16x8 b1 = *(const bf16x8*)&mrow[32 + kg * 8];
      bf16x8 b2 = *(const bf16x8*)&mrow[64 + kg * 8];
      bf16x8 b3 = *(const bf16x8*)&mrow[96 + kg * 8];
      f32x4 acc = (f32x4){0.f, 0.f, 0.f, 0.f};
      acc = __builtin_amdgcn_mfma_f32_16x16x32_bf16(a0, b0, acc, 0, 0, 0);
      acc = __builtin_amdgcn_mfma_f32_16x16x32_bf16(a1, b1, acc, 0, 0, 0);
      acc = __builtin_amdgcn_mfma_f32_16x16x32_bf16(a2, b2, acc, 0, 0, 0);
      acc = __builtin_amdgcn_mfma_f32_16x16x32_bf16(a3, b3, acc, 0, 0, 0);
      #pragma unroll
      for (int r = 0; r < 4; ++r)
        yrow[(mt * 16 + kg * 4 + r) * 64 + j * 16 + n15] = f2bf(geluf(acc[r]));
    }
  }
}

// ---------- fused: GEMM(yT * W) + GLU + residual + next-layer LN -> z ----------
// 32 l-rows x 512 cols; Bs staged async via global_load_lds (r7 structure, the proven
// latency-hiding path); XCD swizzle keeps sibling half-lines on one XCD; residual g_x
// prefetched into registers before the K-loop (block exclusively owns its 32 rows).
__global__ __launch_bounds__(256, 4) void k_gemmglu(int layer, const float* __restrict__ bias,
                                                    const float* __restrict__ gam,
                                                    const float* __restrict__ bet,
                                                    int writez) {
  __shared__ __attribute__((aligned(16))) unsigned short As[32 * 40];    // 2.5 KB [l][k]
  __shared__ __attribute__((aligned(16))) unsigned short BX[512 * 32];   // 32 KB: Bs | Xs(bf16)
  __shared__ float Rs1[32][4], Rs2[32][4], muS[32], rsS[32];
  unsigned short* Bs = BX;                       // [n=512][k=32]
  unsigned short* Xs = BX;                       // [col=256][rl] pitch 34
  const int tid = threadIdx.x, wave = tid >> 6, lane = tid & 63;
  const int n15 = lane & 15, kg = lane >> 4, q2 = kg * 8;
  const int ltile = ((blockIdx.x & 7) << 7) | (blockIdx.x >> 3);
  const int row0 = ltile * 32;
  const int b = row0 >> 11, l0 = row0 & 2047;
  const unsigned short* Wt = g_Wt + (long)layer * 131072;
  const unsigned short* ybase = g_ybh + (long)b * HD * LL + l0;
  const int hl = tid >> 3, sg = tid & 7;         // A-staging: h-row, l-seg
  // prefetch residual x (overlaps with the whole K-loop)
  float xold[4][2][4];
  #pragma unroll
  for (int j = 0; j < 4; ++j) {
    int col = wave * 64 + j * 16 + n15;
    #pragma unroll
    for (int mt = 0; mt < 2; ++mt)
      #pragma unroll
      for (int r = 0; r < 4; ++r)
        xold[j][mt][r] = g_x[(long)(row0 + mt * 16 + kg * 4 + r) * 256 + col];
  }
  f32x4 acc[2][8];
  #pragma unroll
  for (int a = 0; a < 2; ++a)
    #pragma unroll
    for (int b2 = 0; b2 < 8; ++b2) acc[a][b2] = (f32x4){0.f, 0.f, 0.f, 0.f};
  for (int k0 = 0; k0 < 256; k0 += 32) {
    __syncthreads();
    // A: ybh[b][k0+hl][l0+sg*4 ..+4] -> As[l][h] (transpose)
    ushort4 av = *(const ushort4*)(ybase + (long)(k0 + hl) * LL + sg * 4);
    As[(sg * 4 + 0) * 40 + hl] = av.x;
    As[(sg * 4 + 1) * 40 + hl] = av.y;
    As[(sg * 4 + 2) * 40 + hl] = av.z;
    As[(sg * 4 + 3) * 40 + hl] = av.w;
    // B: all 512 n-rows, 32 k (async direct-to-LDS)
    #pragma unroll
    for (int it = 0; it < 8; ++it) {
      int slot = it * 256 + wave * 64 + lane;    // n = slot>>2, ko = (slot&3)*8
      int n = slot >> 2, ko = (slot & 3) * 8;
      __builtin_amdgcn_global_load_lds(
        (const __attribute__((address_space(1))) unsigned int*)(Wt + (long)n * 256 + k0 + ko),
        (__attribute__((address_space(3))) unsigned int*)(Bs + (it * 256 + wave * 64) * 8),
        16, 0, 0);
    }
    __syncthreads();
    bf16x8 af0 = *(const bf16x8*)&As[n15 * 40 + q2];
    bf16x8 af1 = *(const bf16x8*)&As[(16 + n15) * 40 + q2];
    #pragma unroll
    for (int j = 0; j < 4; ++j) {
      int nc = wave * 64 + j * 16 + n15;
      bf16x8 ba = *(const bf16x8*)&Bs[nc * 32 + q2];
      acc[0][j] = __builtin_amdgcn_mfma_f32_16x16x32_bf16(af0, ba, acc[0][j], 0, 0, 0);
      acc[1][j] = __builtin_amdgcn_mfma_f32_16x16x32_bf16(af1, ba, acc[1][j], 0, 0, 0);
      bf16x8 bg = *(const bf16x8*)&Bs[(nc + 256) * 32 + q2];
      acc[0][4 + j] = __builtin_amdgcn_mfma_f32_16x16x32_bf16(af0, bg, acc[0][4 + j], 0, 0, 0);
      acc[1][4 + j] = __builtin_amdgcn_mfma_f32_16x16x32_bf16(af1, bg, acc[1][4 + j], 0, 0, 0);
    }
  }
  __syncthreads();                  // Bs dead; Xs may be written now
  // epilogue: GLU + residual (+ stage xn bf16, exact fp32 row sums)
  float s1l[2][4], s2l[2][4];
  #pragma unroll
  for (int mt = 0; mt < 2; ++mt)
    #pragma unroll
    for (int r = 0; r < 4; ++r) { s1l[mt][r] = 0.f; s2l[mt][r] = 0.f; }
  #pragma unroll
  for (int j = 0; j < 4; ++j) {
    int col = wave * 64 + j * 16 + n15;
    float ba = bias[col], bg = bias[col + 256];
    #pragma unroll
    for (int mt = 0; mt < 2; ++mt) {
      #pragma unroll
      for (int r = 0; r < 4; ++r) {
        int rl = mt * 16 + kg * 4 + r;
        float a = acc[mt][j][r] + ba;
        float g = acc[mt][4 + j][r] + bg;
        float xn = xold[j][mt][r] + a * sigf(g);
        g_x[(long)(row0 + rl) * 256 + col] = xn;
        if (writez) {
          Xs[col * 34 + rl] = f2bf(xn);
          s1l[mt][r] += xn; s2l[mt][r] += xn * xn;
        }
      }
    }
  }
  if (!writez) return;
  #pragma unroll
  for (int mt = 0; mt < 2; ++mt)
    #pragma unroll
    for (int r = 0; r < 4; ++r) {
      #pragma unroll
      for (int off = 1; off < 16; off <<= 1) {
        s1l[mt][r] += __shfl_xor(s1l[mt][r], off);
        s2l[mt][r] += __shfl_xor(s2l[mt][r], off);
      }
    }
  if (n15 == 0) {
    #pragma unroll
    for (int mt = 0; mt < 2; ++mt)
      #pragma unroll
      for (int r = 0; r < 4; ++r) {
        Rs1[mt * 16 + kg * 4 + r][wave] = s1l[mt][r];
        Rs2[mt * 16 + kg * 4 + r][wave] = s2l[mt][r];
      }
  }
  __syncthreads();
  if (tid < 32) {
    float s1 = Rs1[tid][0] + Rs1[tid][1] + Rs1[tid][2] + Rs1[tid][3];
    float s2 = Rs2[tid][0] + Rs2[tid][1] + Rs2[tid][2] + Rs2[tid][3];
    float mu = s1 * (1.0f / HD);
    float rs = rsqrtf(s2 * (1.0f / HD) - mu * mu + 1e-5f);
    muS[tid] = mu; rsS[tid] = rs;
  }
  __syncthreads();
  {
    int hh = tid;
    float gm = gam[hh], bt = bet[hh];
    const unsigned short* xrow = &Xs[hh * 34];
    union { unsigned short u[32]; ulonglong2 v4[4]; } pk;
    #pragma unroll
    for (int rl = 0; rl < 32; ++rl)
      pk.u[rl] = f2bf((bf2f(xrow[rl]) - muS[rl]) * rsS[rl] * gm + bt);
    unsigned short* zp = g_zbh + ((long)(b * HD + hh)) * LL + l0;
    #pragma unroll
    for (int q = 0; q < 4; ++q) *(ulonglong2*)(zp + q * 8) = pk.v4[q];
  }
}

// ---------- final LN + partial pool ----------
__global__ __launch_bounds__(256) void k_lnpool(const float* __restrict__ gam,
                                                const float* __restrict__ bet) {
  __shared__ float red[4][256];
  const int bid = blockIdx.x;
  const int b = bid >> 4, s = bid & 15;
  const int tid = threadIdx.x, w = tid >> 6, lane = tid & 63;
  float4 gv = *(const float4*)(gam + lane * 4);
  float4 bv = *(const float4*)(bet + lane * 4);
  float a0 = 0, a1 = 0, a2 = 0, a3 = 0;
  for (int r = 0; r < 32; ++r) {
    int l = s * 128 + w * 32 + r;
    float4 v = *(const float4*)(g_x + ((long)b * LL + l) * HD + lane * 4);
    float s1 = v.x + v.y + v.z + v.w;
    float s2 = v.x * v.x + v.y * v.y + v.z * v.z + v.w * v.w;
    #pragma unroll
    for (int off = 32; off; off >>= 1) { s1 += __shfl_xor(s1, off); s2 += __shfl_xor(s2, off); }
    float mu = s1 * (1.0f / HD);
    float rs = rsqrtf(s2 * (1.0f / HD) - mu * mu + 1e-5f);
    a0 += (v.x - mu) * rs * gv.x + bv.x;
    a1 += (v.y - mu) * rs * gv.y + bv.y;
    a2 += (v.z - mu) * rs * gv.z + bv.z;
    a3 += (v.w - mu) * rs * gv.w + bv.w;
  }
  red[w][lane * 4 + 0] = a0; red[w][lane * 4 + 1] = a1;
  red[w][lane * 4 + 2] = a2; red[w][lane * 4 + 3] = a3;
  __syncthreads();
  g_pp[(long)bid * HD + tid] = red[0][tid] + red[1][tid] + red[2][tid] + red[3][tid];
}

// ---------- classifier ----------
__global__ __launch_bounds__(256) void k_cls(const float* __restrict__ Wc,
                                             const float* __restrict__ bc,
                                             float* __restrict__ out) {
  __shared__ float pl[256];
  const int b = blockIdx.x, tid = threadIdx.x;
  float p = 0.f;
  #pragma unroll
  for (int s = 0; s < 16; ++s) p += g_pp[((long)b * 16 + s) * HD + tid];
  pl[tid] = p * (1.0f / LL);
  __syncthreads();
  if (tid < NCLS) {
    float acc = bc[tid];
    for (int h = 0; h < HD; ++h) acc += pl[h] * Wc[h * NCLS + tid];
    out[b * NCLS + tid] = acc;
  }
}

extern "C" void kernel_launch(void* const* d_in, const int* in_sizes, int n_in,
                              void* d_out, int out_size, void* d_ws, size_t ws_size,
                              hipStream_t stream) {
  (void)in_sizes; (void)n_in; (void)d_ws; (void)ws_size; (void)out_size;
  const float* x_in   = (const float*)d_in[0];
  const float* W_in   = (const float*)d_in[1];
  const float* b_in   = (const float*)d_in[2];
  const float* log_dt = (const float*)d_in[3];
  const float* A_re   = (const float*)d_in[4];
  const float* A_im   = (const float*)d_in[5];
  const float* B_re   = (const float*)d_in[6];
  const float* B_im   = (const float*)d_in[7];
  const float* C_re   = (const float*)d_in[8];
  const float* C_im   = (const float*)d_in[9];
  const float* Dd     = (const float*)d_in[10];
  const float* W_out  = (const float*)d_in[11];
  const float* b_out  = (const float*)d_in[12];
  const float* ln_s   = (const float*)d_in[13];
  const float* ln_b   = (const float*)d_in[14];
  const float* lnf_s  = (const float*)d_in[15];
  const float* lnf_b  = (const float*)d_in[16];
  const float* W_cls  = (const float*)d_in[17];
  const float* b_cl   = (const float*)d_in[18];
  float* out = (float*)d_out;

  k_precomp<<<192, 256, 0, stream>>>(log_dt, A_re, A_im, B_re, B_im, C_re, C_im);
  k_precompK<<<384, 256, 0, stream>>>();
  k_precompM<<<49152, 256, 0, stream>>>(Dd);
  k_precompA2<<<24576, 256, 0, stream>>>();
  k_prepW<<<768, 256, 0, stream>>>(W_out);
  k_prepWin<<<128, 256, 0, stream>>>(W_in);
  k_castin<<<2048, 256, 0, stream>>>(x_in);
  k_gemmin<<<256, 256, 0, stream>>>(b_in);
  k_ln<<<1024, 256, 0, stream>>>(ln_s, ln_b);           // layer-0 prenorm
  for (int i = 0; i < NLAYERS; ++i) {
    int nl = (i + 1 < NLAYERS) ? (i + 1) : 0;
    k_ssm<<<4096, 256, 0, stream>>>(i);
    k_gemmglu<<<1024, 256, 0, stream>>>(i, b_out + i * 2 * HD,
                                        ln_s + nl * HD, ln_b + nl * HD,
                                        (i + 1 < NLAYERS) ? 1 : 0);
  }
  k_lnpool<<<256, 256, 0, stream>>>(lnf_s, lnf_b);
  k_cls<<<16, 256, 0, stream>>>(W_cls, b_cl, out);
}

// Round 10
// 669.405 us; speedup vs baseline: 1.1489x; 1.1489x over previous
//
#include <hip/hip_runtime.h>
#include <math.h>

#define NLAYERS 6
#define HD 256
#define NS 32
#define NCLS 50
#define BB 16
#define LL 2048
#define TT 64
#define CC 32

typedef __attribute__((ext_vector_type(8))) short bf16x8;
typedef __attribute__((ext_vector_type(4))) float f32x4;

// ---- static device workspaces ----
__device__ __attribute__((aligned(16))) float g_x [8388608];   // [B][L][H] residual stream (fp32)
__device__ __attribute__((aligned(16))) float g_Vt[6389760];   // [l][h][n][65][2] : w^t, t=0..64
__device__ __attribute__((aligned(16))) float g_Kt[98304];     // [l][h][64] kernel taps
__device__ __attribute__((aligned(16))) float g_E0[98304];     // [l][h][n][2] : C*dB
__device__ __attribute__((aligned(16))) float g_pp[65536];     // [B][16][H] pool partials
__device__ __attribute__((aligned(16))) unsigned short g_zbh[8388608]; // z bf16 [B][H][L]
__device__ __attribute__((aligned(16))) unsigned short g_Mt [12582912];// [l][h][t=64][k=128] bf16 (TK;TC)^T, D folded
__device__ __attribute__((aligned(16))) unsigned short g_TAt[6291456]; // [l][h][p=64][t=64] bf16 TA^T
__device__ __attribute__((aligned(16))) unsigned short g_ybh[8388608]; // y bf16 [B][H][L]
__device__ __attribute__((aligned(16))) unsigned short g_Wt [786432];  // Wt bf16 [l][n=512][k=256]
__device__ __attribute__((aligned(16))) unsigned short g_xb [4194304]; // x_in bf16 [32768][128]
__device__ __attribute__((aligned(16))) unsigned short g_Wint[32768];  // W_in^T bf16 [n=256][k=128]

__device__ __forceinline__ float sigf(float x) { return 1.0f / (1.0f + __expf(-x)); }
__device__ __forceinline__ float geluf(float x) {
  float t = 0.7978845608028654f * (x + 0.044715f * x * x * x);
  float e = __expf(2.0f * t);
  float th = 1.0f - 2.0f / (e + 1.0f);
  return 0.5f * x * (1.0f + th);
}
__device__ __forceinline__ unsigned short f2bf(float f) {
  unsigned u = __float_as_uint(f);
  unsigned r = (u + 0x7FFFu + ((u >> 16) & 1u)) >> 16;
  return (unsigned short)r;
}
__device__ __forceinline__ float bf2f(unsigned short u) {
  return __uint_as_float(((unsigned)u) << 16);
}

// ---------- precompute: w, E0 = C*dB, power table w^t ----------
__global__ void k_precomp(const float* __restrict__ log_dt,
                          const float* __restrict__ A_re, const float* __restrict__ A_im,
                          const float* __restrict__ B_re, const float* __restrict__ B_im,
                          const float* __restrict__ C_re, const float* __restrict__ C_im) {
  int id = blockIdx.x * 256 + threadIdx.x;
  if (id >= NLAYERS * HD * NS) return;
  int h = (id / NS) % HD;
  int i = id / (NS * HD);
  float dt = expf(log_dt[i * HD + h]);
  float ar = A_re[id], ai = A_im[id];
  float dr = dt * ar, di = dt * ai;
  float er = expf(dr);
  float wr = er * cosf(di), wi = er * sinf(di);
  float inv = 1.0f / (ar * ar + ai * ai);
  float mr = wr - 1.0f, mi = wi;
  float qr = (mr * ar + mi * ai) * inv;
  float qi = (mi * ar - mr * ai) * inv;
  float br = B_re[id], bi = B_im[id];
  float dbr = br * qr - bi * qi, dbi = br * qi + bi * qr;
  float cr = C_re[id], ci = C_im[id];
  g_E0[id * 2 + 0] = cr * dbr - ci * dbi;
  g_E0[id * 2 + 1] = cr * dbi + ci * dbr;
  float pr = 1.0f, pi = 0.0f;
  long base = (long)id * 65;
  for (int t = 0; t <= 64; ++t) {
    g_Vt[(base + t) * 2 + 0] = pr;
    g_Vt[(base + t) * 2 + 1] = pi;
    float nr = pr * wr - pi * wi;
    pi = pr * wi + pi * wr;
    pr = nr;
  }
}

__global__ void k_precompK() {
  int id = blockIdx.x * 256 + threadIdx.x;
  if (id >= NLAYERS * HD * TT) return;
  int t = id % TT;
  int lh = id / TT;
  float acc = 0.f;
  const float* e = g_E0 + (long)lh * NS * 2;
  const float* v = g_Vt + ((long)lh * NS * 65 + t) * 2;
  for (int n = 0; n < NS; ++n)
    acc += e[n * 2] * v[n * 130] - e[n * 2 + 1] * v[n * 130 + 1];
  g_Kt[id] = 2.0f * acc;
}

// Mt[l][h][t][k] bf16: k<64 -> TK[s=k][t] (+D at k==t); k>=64 -> TC[p=k-64][t]
__global__ void k_precompM(const float* __restrict__ Dd) {
  int id = blockIdx.x * 256 + threadIdx.x;     // 12582912
  int k = id & 127;
  int t = (id >> 7) & 63;
  int lh = id >> 13;
  float v;
  if (k < 64) {
    v = (t >= k) ? g_Kt[(long)lh * 64 + (t - k)] : 0.f;
    if (k == t) v += Dd[lh];
  } else {
    int p = k - 64, n = p >> 1;
    const float2 w = ((const float2*)g_Vt)[((long)lh * NS + n) * 65 + (t + 1)];
    v = (p & 1) ? (-2.f * w.y) : (2.f * w.x);
  }
  g_Mt[id] = f2bf(v);
}

// TAt[l][h][p][t] = TA[t][p] bf16
__global__ void k_precompA2() {
  int id = blockIdx.x * 256 + threadIdx.x;     // 6291456
  int t = id & 63;
  int p = (id >> 6) & 63;
  int lh = id >> 12;
  int n = p >> 1;
  const float2 w = ((const float2*)g_Vt)[((long)lh * NS + n) * 65 + (63 - t)];
  g_TAt[id] = f2bf((p & 1) ? w.y : w.x);
}

// ---------- W_out -> Wt bf16 [l][n][k] ----------
__global__ __launch_bounds__(256) void k_prepW(const float* __restrict__ W_out) {
  __shared__ float T[32][33];
  int bid = blockIdx.x;
  int nt = bid & 15, kt = (bid >> 4) & 7, l = bid >> 7;
  int t = threadIdx.x;
  int tr = t >> 3, tc = t & 7;
  const float* src = W_out + (long)l * 131072 + (long)(kt * 32) * 512 + nt * 32;
  float4 v = *(const float4*)(src + (long)tr * 512 + tc * 4);
  T[tr][tc * 4 + 0] = v.x; T[tr][tc * 4 + 1] = v.y;
  T[tr][tc * 4 + 2] = v.z; T[tr][tc * 4 + 3] = v.w;
  __syncthreads();
  ushort4 o;
  o.x = f2bf(T[tc * 4 + 0][tr]); o.y = f2bf(T[tc * 4 + 1][tr]);
  o.z = f2bf(T[tc * 4 + 2][tr]); o.w = f2bf(T[tc * 4 + 3][tr]);
  *(ushort4*)(g_Wt + ((long)l * 512 + nt * 32 + tr) * 256 + kt * 32 + tc * 4) = o;
}

// ---------- W_in [k=128][n=256] -> Wint bf16 [n][k] ----------
__global__ void k_prepWin(const float* __restrict__ W_in) {
  int k = blockIdx.x, n = threadIdx.x;
  g_Wint[n * 128 + k] = f2bf(W_in[k * 256 + n]);
}

// ---------- x_in fp32 -> bf16 ----------
__global__ void k_castin(const float* __restrict__ xin) {
  long base = ((long)blockIdx.x * 256 + threadIdx.x) * 8;
  float4 v0 = *(const float4*)(xin + base);
  float4 v1 = *(const float4*)(xin + base + 4);
  union { unsigned short u[8]; ulonglong2 v; } pk;
  pk.u[0] = f2bf(v0.x); pk.u[1] = f2bf(v0.y); pk.u[2] = f2bf(v0.z); pk.u[3] = f2bf(v0.w);
  pk.u[4] = f2bf(v1.x); pk.u[5] = f2bf(v1.y); pk.u[6] = f2bf(v1.z); pk.u[7] = f2bf(v1.w);
  *(ulonglong2*)(g_xb + base) = pk.v;
}

// ---------- input GEMM (bf16 MFMA): g_x[32768,256] = xb[32768,128]*Wint^T + b ----------
__global__ __launch_bounds__(256) void k_gemmin(const float* __restrict__ bias) {
  __shared__ __attribute__((aligned(16))) unsigned short As[128 * 32];
  __shared__ __attribute__((aligned(16))) unsigned short Bs[256 * 32];
  const int tid = threadIdx.x;
  const int wave = tid >> 6, lane = tid & 63;
  const int m0 = blockIdx.x * 128;
  const int wm = wave & 1, wn = wave >> 1;
  const int n15 = lane & 15, kg = lane >> 4, q2 = kg * 8;
  f32x4 acc[4][8];
  #pragma unroll
  for (int a = 0; a < 4; ++a)
    #pragma unroll
    for (int b2 = 0; b2 < 8; ++b2) acc[a][b2] = (f32x4){0.f, 0.f, 0.f, 0.f};
  for (int k0 = 0; k0 < 128; k0 += 32) {
    __syncthreads();
    #pragma unroll
    for (int it = 0; it < 2; ++it) {
      int slot = it * 256 + wave * 64 + lane;
      int m = slot >> 2, ko = (slot & 3) * 8;
      __builtin_amdgcn_global_load_lds(
        (const __attribute__((address_space(1))) unsigned int*)(g_xb + (long)(m0 + m) * 128 + k0 + ko),
        (__attribute__((address_space(3))) unsigned int*)(As + (it * 256 + wave * 64) * 8),
        16, 0, 0);
    }
    #pragma unroll
    for (int it = 0; it < 4; ++it) {
      int slot = it * 256 + wave * 64 + lane;
      int n = slot >> 2, ko = (slot & 3) * 8;
      __builtin_amdgcn_global_load_lds(
        (const __attribute__((address_space(1))) unsigned int*)(g_Wint + (long)n * 128 + k0 + ko),
        (__attribute__((address_space(3))) unsigned int*)(Bs + (it * 256 + wave * 64) * 8),
        16, 0, 0);
    }
    __syncthreads();
    bf16x8 af[4], bn[8];
    #pragma unroll
    for (int mt = 0; mt < 4; ++mt)
      af[mt] = *(const bf16x8*)&As[(wm * 64 + mt * 16 + n15) * 32 + q2];
    #pragma unroll
    for (int j = 0; j < 8; ++j)
      bn[j] = *(const bf16x8*)&Bs[(wn * 128 + j * 16 + n15) * 32 + q2];
    #pragma unroll
    for (int mt = 0; mt < 4; ++mt)
      #pragma unroll
      for (int j = 0; j < 8; ++j)
        acc[mt][j] = __builtin_amdgcn_mfma_f32_16x16x32_bf16(af[mt], bn[j], acc[mt][j], 0, 0, 0);
  }
  #pragma unroll
  for (int j = 0; j < 8; ++j) {
    int col = wn * 128 + j * 16 + n15;
    float bb = bias[col];
    #pragma unroll
    for (int mt = 0; mt < 4; ++mt)
      #pragma unroll
      for (int r = 0; r < 4; ++r) {
        int row = m0 + wm * 64 + mt * 16 + kg * 4 + r;
        g_x[(long)row * 256 + col] = acc[mt][j][r] + bb;
      }
  }
}

// ---------- LayerNorm over H -> z bf16 [B][H][L]; only for layer 0 ----------
__global__ __launch_bounds__(256) void k_ln(const float* __restrict__ gam,
                                            const float* __restrict__ bet) {
  __shared__ unsigned short S[32 * 264];
  const int bid = blockIdx.x;                  // 1024
  const int b = bid >> 6, l0 = (bid & 63) << 5;
  const int tid = threadIdx.x, w = tid >> 6, lane = tid & 63;
  float4 gv = *(const float4*)(gam + lane * 4);
  float4 bv = *(const float4*)(bet + lane * 4);
  for (int r = 0; r < 8; ++r) {
    int ll = w * 8 + r;
    float4 v = *(const float4*)(g_x + ((long)(b * LL + l0 + ll)) * HD + lane * 4);
    float s1 = v.x + v.y + v.z + v.w;
    float s2 = v.x * v.x + v.y * v.y + v.z * v.z + v.w * v.w;
    #pragma unroll
    for (int off = 32; off; off >>= 1) { s1 += __shfl_xor(s1, off); s2 += __shfl_xor(s2, off); }
    float mu = s1 * (1.0f / HD);
    float rs = rsqrtf(s2 * (1.0f / HD) - mu * mu + 1e-5f);
    ushort4 o;
    o.x = f2bf((v.x - mu) * rs * gv.x + bv.x);
    o.y = f2bf((v.y - mu) * rs * gv.y + bv.y);
    o.z = f2bf((v.z - mu) * rs * gv.z + bv.z);
    o.w = f2bf((v.w - mu) * rs * gv.w + bv.w);
    *(ushort4*)&S[ll * 264 + lane * 4] = o;
  }
  __syncthreads();
  unsigned short* zp = g_zbh + ((long)(b * HD + tid)) * LL + l0;
  #pragma unroll
  for (int seg = 0; seg < 4; ++seg) {
    union { unsigned short u[8]; ulonglong2 v; } pk;
    #pragma unroll
    for (int i = 0; i < 8; ++i) pk.u[i] = S[(seg * 8 + i) * 264 + tid];
    *(ulonglong2*)(zp + seg * 8) = pk.v;
  }
}

// ---------- fused SSM: phaseA (MFMA) + chunk scan + phaseC (MFMA), one block per (b,h) ----------
__global__ __launch_bounds__(256) void k_ssm(int layer) {
  __shared__ __attribute__((aligned(16))) unsigned short Zs[32 * 72];   // z [c][t]
  __shared__ __attribute__((aligned(16))) unsigned short Ts[64 * 72];   // TA^T [p][t] | Ss fp32 [c][p] pitch 68
  __shared__ __attribute__((aligned(16))) unsigned short Ms[64 * 136];  // Mt [t][k]
  __shared__ __attribute__((aligned(16))) unsigned short Gs[32 * 72];   // G [c][p]
  float* Ss = (float*)Ts;
  const int tid = threadIdx.x, wave = tid >> 6, lane = tid & 63;
  const int h = blockIdx.x & 255, b = blockIdx.x >> 8;
  const long lh = (long)layer * HD + h;
  {
    int c = tid >> 3, off = (tid & 7) * 8;
    *(ulonglong2*)&Zs[c * 72 + off] =
        *(const ulonglong2*)(g_zbh + ((long)(b * HD + h)) * LL + c * 64 + off);
  }
  const unsigned short* Tg = g_TAt + lh * 4096;
  #pragma unroll
  for (int i = 0; i < 2; ++i) {
    int seg = tid + i * 256;
    int row = seg >> 3, sc = (seg & 7) * 8;
    *(ulonglong2*)&Ts[row * 72 + sc] = *(const ulonglong2*)(Tg + row * 64 + sc);
  }
  const unsigned short* Mg = g_Mt + lh * 8192;
  #pragma unroll
  for (int i = 0; i < 4; ++i) {
    int seg = tid + i * 256;
    int row = seg >> 4, sc = (seg & 15) * 8;
    *(ulonglong2*)&Ms[row * 136 + sc] = *(const ulonglong2*)(Mg + row * 128 + sc);
  }
  __syncthreads();
  const int n15 = lane & 15, kg = lane >> 4;
  const int mt = wave & 1;
  const int jb = (wave >> 1) * 2;
  const int c = mt * 16 + n15;
  {
    bf16x8 a0 = *(const bf16x8*)&Zs[c * 72 + kg * 8];
    bf16x8 a1 = *(const bf16x8*)&Zs[c * 72 + 32 + kg * 8];
    bf16x8 tb0[2], tb1[2];
    #pragma unroll
    for (int jj = 0; jj < 2; ++jj) {
      int j = jb + jj;
      tb0[jj] = *(const bf16x8*)&Ts[(j * 16 + n15) * 72 + kg * 8];
      tb1[jj] = *(const bf16x8*)&Ts[(j * 16 + n15) * 72 + 32 + kg * 8];
    }
    f32x4 accA[2];
    #pragma unroll
    for (int jj = 0; jj < 2; ++jj) {
      accA[jj] = (f32x4){0.f, 0.f, 0.f, 0.f};
      accA[jj] = __builtin_amdgcn_mfma_f32_16x16x32_bf16(a0, tb0[jj], accA[jj], 0, 0, 0);
      accA[jj] = __builtin_amdgcn_mfma_f32_16x16x32_bf16(a1, tb1[jj], accA[jj], 0, 0, 0);
    }
    __syncthreads();                     // all Ts reads done; safe to alias as Ss
    #pragma unroll
    for (int jj = 0; jj < 2; ++jj) {
      int j = jb + jj;
      #pragma unroll
      for (int r = 0; r < 4; ++r)
        Ss[(mt * 16 + kg * 4 + r) * 68 + j * 16 + n15] = accA[jj][r];
    }
  }
  __syncthreads();
  if (wave == 0 && lane < 32) {
    int n = lane;
    long vb = (lh * NS + n) * 65;
    float wtr = g_Vt[vb * 2 + 128], wti = g_Vt[vb * 2 + 129];
    float e0r = g_E0[(lh * NS + n) * 2], e0i = g_E0[(lh * NS + n) * 2 + 1];
    float sr = 0.f, si = 0.f;
    for (int cc = 0; cc < CC; ++cc) {
      float er = Ss[cc * 68 + 2 * n], ei = Ss[cc * 68 + 2 * n + 1];
      Gs[cc * 72 + 2 * n]     = f2bf(e0r * sr - e0i * si);
      Gs[cc * 72 + 2 * n + 1] = f2bf(e0r * si + e0i * sr);
      float nr = er + wtr * sr - wti * si;
      si      = ei + wtr * si + wti * sr;
      sr = nr;
    }
  }
  __syncthreads();
  {
    bf16x8 a0 = *(const bf16x8*)&Zs[c * 72 + kg * 8];
    bf16x8 a1 = *(const bf16x8*)&Zs[c * 72 + 32 + kg * 8];
    bf16x8 a2 = *(const bf16x8*)&Gs[c * 72 + kg * 8];
    bf16x8 a3 = *(const bf16x8*)&Gs[c * 72 + 32 + kg * 8];
    unsigned short* yrow = g_ybh + ((long)(b * HD + h)) * LL;
    #pragma unroll
    for (int jj = 0; jj < 2; ++jj) {
      int j = jb + jj;
      const unsigned short* mrow = &Ms[(j * 16 + n15) * 136];
      bf16x8 b0 = *(const bf16x8*)&mrow[kg * 8];
      bf16x8 b1 = *(const bf16x8*)&mrow[32 + kg * 8];
      bf16x8 b2 = *(const bf16x8*)&mrow[64 + kg * 8];
      bf16x8 b3 = *(const bf16x8*)&mrow[96 + kg * 8];
      f32x4 acc = (f32x4){0.f, 0.f, 0.f, 0.f};
      acc = __builtin_amdgcn_mfma_f32_16x16x32_bf16(a0, b0, acc, 0, 0, 0);
      acc = __builtin_amdgcn_mfma_f32_16x16x32_bf16(a1, b1, acc, 0, 0, 0);
      acc = __builtin_amdgcn_mfma_f32_16x16x32_bf16(a2, b2, acc, 0, 0, 0);
      acc = __builtin_amdgcn_mfma_f32_16x16x32_bf16(a3, b3, acc, 0, 0, 0);
      #pragma unroll
      for (int r = 0; r < 4; ++r)
        yrow[(mt * 16 + kg * 4 + r) * 64 + j * 16 + n15] = f2bf(geluf(acc[r]));
    }
  }
}

// ---------- fused: GEMM(yT * W) + GLU + residual + next-layer LN -> z ----------
// 32 l-rows x 512 cols; Bs staged async (r7 latency-hiding) + XCD swizzle (r8 traffic cut)
// + bf16 Xs. Residual g_x read inline in epilogue (r9's register prefetch spilled -> reverted).
__global__ __launch_bounds__(256, 4) void k_gemmglu(int layer, const float* __restrict__ bias,
                                                    const float* __restrict__ gam,
                                                    const float* __restrict__ bet,
                                                    int writez) {
  __shared__ __attribute__((aligned(16))) unsigned short As[32 * 40];    // 2.5 KB [l][k]
  __shared__ __attribute__((aligned(16))) unsigned short BX[512 * 32];   // 32 KB: Bs | Xs(bf16)
  __shared__ float Rs1[32][4], Rs2[32][4], muS[32], rsS[32];
  unsigned short* Bs = BX;                       // [n=512][k=32]
  unsigned short* Xs = BX;                       // [col=256][rl] pitch 34
  const int tid = threadIdx.x, wave = tid >> 6, lane = tid & 63;
  const int n15 = lane & 15, kg = lane >> 4, q2 = kg * 8;
  const int ltile = ((blockIdx.x & 7) << 7) | (blockIdx.x >> 3);
  const int row0 = ltile * 32;
  const int b = row0 >> 11, l0 = row0 & 2047;
  const unsigned short* Wt = g_Wt + (long)layer * 131072;
  const unsigned short* ybase = g_ybh + (long)b * HD * LL + l0;
  const int hl = tid >> 3, sg = tid & 7;         // A-staging: h-row, l-seg
  f32x4 acc[2][8];
  #pragma unroll
  for (int a = 0; a < 2; ++a)
    #pragma unroll
    for (int b2 = 0; b2 < 8; ++b2) acc[a][b2] = (f32x4){0.f, 0.f, 0.f, 0.f};
  for (int k0 = 0; k0 < 256; k0 += 32) {
    __syncthreads();
    // A: ybh[b][k0+hl][l0+sg*4 ..+4] -> As[l][h] (transpose)
    ushort4 av = *(const ushort4*)(ybase + (long)(k0 + hl) * LL + sg * 4);
    As[(sg * 4 + 0) * 40 + hl] = av.x;
    As[(sg * 4 + 1) * 40 + hl] = av.y;
    As[(sg * 4 + 2) * 40 + hl] = av.z;
    As[(sg * 4 + 3) * 40 + hl] = av.w;
    // B: all 512 n-rows, 32 k (async direct-to-LDS)
    #pragma unroll
    for (int it = 0; it < 8; ++it) {
      int slot = it * 256 + wave * 64 + lane;    // n = slot>>2, ko = (slot&3)*8
      int n = slot >> 2, ko = (slot & 3) * 8;
      __builtin_amdgcn_global_load_lds(
        (const __attribute__((address_space(1))) unsigned int*)(Wt + (long)n * 256 + k0 + ko),
        (__attribute__((address_space(3))) unsigned int*)(Bs + (it * 256 + wave * 64) * 8),
        16, 0, 0);
    }
    __syncthreads();
    bf16x8 af0 = *(const bf16x8*)&As[n15 * 40 + q2];
    bf16x8 af1 = *(const bf16x8*)&As[(16 + n15) * 40 + q2];
    #pragma unroll
    for (int j = 0; j < 4; ++j) {
      int nc = wave * 64 + j * 16 + n15;
      bf16x8 ba = *(const bf16x8*)&Bs[nc * 32 + q2];
      acc[0][j] = __builtin_amdgcn_mfma_f32_16x16x32_bf16(af0, ba, acc[0][j], 0, 0, 0);
      acc[1][j] = __builtin_amdgcn_mfma_f32_16x16x32_bf16(af1, ba, acc[1][j], 0, 0, 0);
      bf16x8 bg = *(const bf16x8*)&Bs[(nc + 256) * 32 + q2];
      acc[0][4 + j] = __builtin_amdgcn_mfma_f32_16x16x32_bf16(af0, bg, acc[0][4 + j], 0, 0, 0);
      acc[1][4 + j] = __builtin_amdgcn_mfma_f32_16x16x32_bf16(af1, bg, acc[1][4 + j], 0, 0, 0);
    }
  }
  __syncthreads();                  // Bs dead; Xs may be written now
  // epilogue: GLU + residual (+ stage xn bf16, exact fp32 row sums)
  float s1l[2][4], s2l[2][4];
  #pragma unroll
  for (int mt = 0; mt < 2; ++mt)
    #pragma unroll
    for (int r = 0; r < 4; ++r) { s1l[mt][r] = 0.f; s2l[mt][r] = 0.f; }
  #pragma unroll
  for (int j = 0; j < 4; ++j) {
    int col = wave * 64 + j * 16 + n15;
    float ba = bias[col], bg = bias[col + 256];
    #pragma unroll
    for (int mt = 0; mt < 2; ++mt) {
      #pragma unroll
      for (int r = 0; r < 4; ++r) {
        int rl = mt * 16 + kg * 4 + r;
        long xi = (long)(row0 + rl) * 256 + col;
        float a = acc[mt][j][r] + ba;
        float g = acc[mt][4 + j][r] + bg;
        float xn = g_x[xi] + a * sigf(g);
        g_x[xi] = xn;
        if (writez) {
          Xs[col * 34 + rl] = f2bf(xn);
          s1l[mt][r] += xn; s2l[mt][r] += xn * xn;
        }
      }
    }
  }
  if (!writez) return;
  #pragma unroll
  for (int mt = 0; mt < 2; ++mt)
    #pragma unroll
    for (int r = 0; r < 4; ++r) {
      #pragma unroll
      for (int off = 1; off < 16; off <<= 1) {
        s1l[mt][r] += __shfl_xor(s1l[mt][r], off);
        s2l[mt][r] += __shfl_xor(s2l[mt][r], off);
      }
    }
  if (n15 == 0) {
    #pragma unroll
    for (int mt = 0; mt < 2; ++mt)
      #pragma unroll
      for (int r = 0; r < 4; ++r) {
        Rs1[mt * 16 + kg * 4 + r][wave] = s1l[mt][r];
        Rs2[mt * 16 + kg * 4 + r][wave] = s2l[mt][r];
      }
  }
  __syncthreads();
  if (tid < 32) {
    float s1 = Rs1[tid][0] + Rs1[tid][1] + Rs1[tid][2] + Rs1[tid][3];
    float s2 = Rs2[tid][0] + Rs2[tid][1] + Rs2[tid][2] + Rs2[tid][3];
    float mu = s1 * (1.0f / HD);
    float rs = rsqrtf(s2 * (1.0f / HD) - mu * mu + 1e-5f);
    muS[tid] = mu; rsS[tid] = rs;
  }
  __syncthreads();
  {
    int hh = tid;
    float gm = gam[hh], bt = bet[hh];
    const unsigned short* xrow = &Xs[hh * 34];
    union { unsigned short u[32]; ulonglong2 v4[4]; } pk;
    #pragma unroll
    for (int rl = 0; rl < 32; ++rl)
      pk.u[rl] = f2bf((bf2f(xrow[rl]) - muS[rl]) * rsS[rl] * gm + bt);
    unsigned short* zp = g_zbh + ((long)(b * HD + hh)) * LL + l0;
    #pragma unroll
    for (int q = 0; q < 4; ++q) *(ulonglong2*)(zp + q * 8) = pk.v4[q];
  }
}

// ---------- final LN + partial pool ----------
__global__ __launch_bounds__(256) void k_lnpool(const float* __restrict__ gam,
                                                const float* __restrict__ bet) {
  __shared__ float red[4][256];
  const int bid = blockIdx.x;
  const int b = bid >> 4, s = bid & 15;
  const int tid = threadIdx.x, w = tid >> 6, lane = tid & 63;
  float4 gv = *(const float4*)(gam + lane * 4);
  float4 bv = *(const float4*)(bet + lane * 4);
  float a0 = 0, a1 = 0, a2 = 0, a3 = 0;
  for (int r = 0; r < 32; ++r) {
    int l = s * 128 + w * 32 + r;
    float4 v = *(const float4*)(g_x + ((long)b * LL + l) * HD + lane * 4);
    float s1 = v.x + v.y + v.z + v.w;
    float s2 = v.x * v.x + v.y * v.y + v.z * v.z + v.w * v.w;
    #pragma unroll
    for (int off = 32; off; off >>= 1) { s1 += __shfl_xor(s1, off); s2 += __shfl_xor(s2, off); }
    float mu = s1 * (1.0f / HD);
    float rs = rsqrtf(s2 * (1.0f / HD) - mu * mu + 1e-5f);
    a0 += (v.x - mu) * rs * gv.x + bv.x;
    a1 += (v.y - mu) * rs * gv.y + bv.y;
    a2 += (v.z - mu) * rs * gv.z + bv.z;
    a3 += (v.w - mu) * rs * gv.w + bv.w;
  }
  red[w][lane * 4 + 0] = a0; red[w][lane * 4 + 1] = a1;
  red[w][lane * 4 + 2] = a2; red[w][lane * 4 + 3] = a3;
  __syncthreads();
  g_pp[(long)bid * HD + tid] = red[0][tid] + red[1][tid] + red[2][tid] + red[3][tid];
}

// ---------- classifier ----------
__global__ __launch_bounds__(256) void k_cls(const float* __restrict__ Wc,
                                             const float* __restrict__ bc,
                                             float* __restrict__ out) {
  __shared__ float pl[256];
  const int b = blockIdx.x, tid = threadIdx.x;
  float p = 0.f;
  #pragma unroll
  for (int s = 0; s < 16; ++s) p += g_pp[((long)b * 16 + s) * HD + tid];
  pl[tid] = p * (1.0f / LL);
  __syncthreads();
  if (tid < NCLS) {
    float acc = bc[tid];
    for (int h = 0; h < HD; ++h) acc += pl[h] * Wc[h * NCLS + tid];
    out[b * NCLS + tid] = acc;
  }
}

extern "C" void kernel_launch(void* const* d_in, const int* in_sizes, int n_in,
                              void* d_out, int out_size, void* d_ws, size_t ws_size,
                              hipStream_t stream) {
  (void)in_sizes; (void)n_in; (void)d_ws; (void)ws_size; (void)out_size;
  const float* x_in   = (const float*)d_in[0];
  const float* W_in   = (const float*)d_in[1];
  const float* b_in   = (const float*)d_in[2];
  const float* log_dt = (const float*)d_in[3];
  const float* A_re   = (const float*)d_in[4];
  const float* A_im   = (const float*)d_in[5];
  const float* B_re   = (const float*)d_in[6];
  const float* B_im   = (const float*)d_in[7];
  const float* C_re   = (const float*)d_in[8];
  const float* C_im   = (const float*)d_in[9];
  const float* Dd     = (const float*)d_in[10];
  const float* W_out  = (const float*)d_in[11];
  const float* b_out  = (const float*)d_in[12];
  const float* ln_s   = (const float*)d_in[13];
  const float* ln_b   = (const float*)d_in[14];
  const float* lnf_s  = (const float*)d_in[15];
  const float* lnf_b  = (const float*)d_in[16];
  const float* W_cls  = (const float*)d_in[17];
  const float* b_cl   = (const float*)d_in[18];
  float* out = (float*)d_out;

  k_precomp<<<192, 256, 0, stream>>>(log_dt, A_re, A_im, B_re, B_im, C_re, C_im);
  k_precompK<<<384, 256, 0, stream>>>();
  k_precompM<<<49152, 256, 0, stream>>>(Dd);
  k_precompA2<<<24576, 256, 0, stream>>>();
  k_prepW<<<768, 256, 0, stream>>>(W_out);
  k_prepWin<<<128, 256, 0, stream>>>(W_in);
  k_castin<<<2048, 256, 0, stream>>>(x_in);
  k_gemmin<<<256, 256, 0, stream>>>(b_in);
  k_ln<<<1024, 256, 0, stream>>>(ln_s, ln_b);           // layer-0 prenorm
  for (int i = 0; i < NLAYERS; ++i) {
    int nl = (i + 1 < NLAYERS) ? (i + 1) : 0;
    k_ssm<<<4096, 256, 0, stream>>>(i);
    k_gemmglu<<<1024, 256, 0, stream>>>(i, b_out + i * 2 * HD,
                                        ln_s + nl * HD, ln_b + nl * HD,
                                        (i + 1 < NLAYERS) ? 1 : 0);
  }
  k_lnpool<<<256, 256, 0, stream>>>(lnf_s, lnf_b);
  k_cls<<<16, 256, 0, stream>>>(W_cls, b_cl, out);
}

// Round 11
// 635.423 us; speedup vs baseline: 1.2103x; 1.0535x over previous
//
#include <hip/hip_runtime.h>
#include <math.h>

#define NLAYERS 6
#define HD 256
#define NS 32
#define NCLS 50
#define BB 16
#define LL 2048
#define TT 64
#define CC 32

typedef __attribute__((ext_vector_type(8))) short bf16x8;
typedef __attribute__((ext_vector_type(4))) float f32x4;

// ---- static device workspaces ----
__device__ __attribute__((aligned(16))) unsigned short g_xh[8388608];  // [B][L][H] residual stream (bf16)
__device__ __attribute__((aligned(16))) float g_Vt[6389760];   // [l][h][n][65][2] : w^t, t=0..64
__device__ __attribute__((aligned(16))) float g_Kt[98304];     // [l][h][64] kernel taps
__device__ __attribute__((aligned(16))) float g_E0[98304];     // [l][h][n][2] : C*dB
__device__ __attribute__((aligned(16))) float g_pp[65536];     // [B][16][H] pool partials
__device__ __attribute__((aligned(16))) unsigned short g_zbh[8388608]; // z bf16 [B][H][L]
__device__ __attribute__((aligned(16))) unsigned short g_Mt [12582912];// [l][h][t=64][k=128] bf16 (TK;TC)^T, D folded
__device__ __attribute__((aligned(16))) unsigned short g_TAt[6291456]; // [l][h][p=64][t=64] bf16 TA^T
__device__ __attribute__((aligned(16))) unsigned short g_ybh[8388608]; // y bf16 [B][H][L]
__device__ __attribute__((aligned(16))) unsigned short g_Wt [786432];  // Wt bf16 [l][n=512][k=256]
__device__ __attribute__((aligned(16))) unsigned short g_xb [4194304]; // x_in bf16 [32768][128]
__device__ __attribute__((aligned(16))) unsigned short g_Wint[32768];  // W_in^T bf16 [n=256][k=128]

__device__ __forceinline__ float sigf(float x) { return 1.0f / (1.0f + __expf(-x)); }
__device__ __forceinline__ float geluf(float x) {
  float t = 0.7978845608028654f * (x + 0.044715f * x * x * x);
  float e = __expf(2.0f * t);
  float th = 1.0f - 2.0f / (e + 1.0f);
  return 0.5f * x * (1.0f + th);
}
__device__ __forceinline__ unsigned short f2bf(float f) {
  unsigned u = __float_as_uint(f);
  unsigned r = (u + 0x7FFFu + ((u >> 16) & 1u)) >> 16;
  return (unsigned short)r;
}
__device__ __forceinline__ float bf2f(unsigned short u) {
  return __uint_as_float(((unsigned)u) << 16);
}

// ---------- precompute: w, E0 = C*dB, power table w^t ----------
__global__ void k_precomp(const float* __restrict__ log_dt,
                          const float* __restrict__ A_re, const float* __restrict__ A_im,
                          const float* __restrict__ B_re, const float* __restrict__ B_im,
                          const float* __restrict__ C_re, const float* __restrict__ C_im) {
  int id = blockIdx.x * 256 + threadIdx.x;
  if (id >= NLAYERS * HD * NS) return;
  int h = (id / NS) % HD;
  int i = id / (NS * HD);
  float dt = expf(log_dt[i * HD + h]);
  float ar = A_re[id], ai = A_im[id];
  float dr = dt * ar, di = dt * ai;
  float er = expf(dr);
  float wr = er * cosf(di), wi = er * sinf(di);
  float inv = 1.0f / (ar * ar + ai * ai);
  float mr = wr - 1.0f, mi = wi;
  float qr = (mr * ar + mi * ai) * inv;
  float qi = (mi * ar - mr * ai) * inv;
  float br = B_re[id], bi = B_im[id];
  float dbr = br * qr - bi * qi, dbi = br * qi + bi * qr;
  float cr = C_re[id], ci = C_im[id];
  g_E0[id * 2 + 0] = cr * dbr - ci * dbi;
  g_E0[id * 2 + 1] = cr * dbi + ci * dbr;
  float pr = 1.0f, pi = 0.0f;
  long base = (long)id * 65;
  for (int t = 0; t <= 64; ++t) {
    g_Vt[(base + t) * 2 + 0] = pr;
    g_Vt[(base + t) * 2 + 1] = pi;
    float nr = pr * wr - pi * wi;
    pi = pr * wi + pi * wr;
    pr = nr;
  }
}

__global__ void k_precompK() {
  int id = blockIdx.x * 256 + threadIdx.x;
  if (id >= NLAYERS * HD * TT) return;
  int t = id % TT;
  int lh = id / TT;
  float acc = 0.f;
  const float* e = g_E0 + (long)lh * NS * 2;
  const float* v = g_Vt + ((long)lh * NS * 65 + t) * 2;
  for (int n = 0; n < NS; ++n)
    acc += e[n * 2] * v[n * 130] - e[n * 2 + 1] * v[n * 130 + 1];
  g_Kt[id] = 2.0f * acc;
}

// Mt[l][h][t][k] bf16: k<64 -> TK[s=k][t] (+D at k==t); k>=64 -> TC[p=k-64][t]
__global__ void k_precompM(const float* __restrict__ Dd) {
  int id = blockIdx.x * 256 + threadIdx.x;     // 12582912
  int k = id & 127;
  int t = (id >> 7) & 63;
  int lh = id >> 13;
  float v;
  if (k < 64) {
    v = (t >= k) ? g_Kt[(long)lh * 64 + (t - k)] : 0.f;
    if (k == t) v += Dd[lh];
  } else {
    int p = k - 64, n = p >> 1;
    const float2 w = ((const float2*)g_Vt)[((long)lh * NS + n) * 65 + (t + 1)];
    v = (p & 1) ? (-2.f * w.y) : (2.f * w.x);
  }
  g_Mt[id] = f2bf(v);
}

// TAt[l][h][p][t] = TA[t][p] bf16
__global__ void k_precompA2() {
  int id = blockIdx.x * 256 + threadIdx.x;     // 6291456
  int t = id & 63;
  int p = (id >> 6) & 63;
  int lh = id >> 12;
  int n = p >> 1;
  const float2 w = ((const float2*)g_Vt)[((long)lh * NS + n) * 65 + (63 - t)];
  g_TAt[id] = f2bf((p & 1) ? w.y : w.x);
}

// ---------- W_out -> Wt bf16 [l][n][k] ----------
__global__ __launch_bounds__(256) void k_prepW(const float* __restrict__ W_out) {
  __shared__ float T[32][33];
  int bid = blockIdx.x;
  int nt = bid & 15, kt = (bid >> 4) & 7, l = bid >> 7;
  int t = threadIdx.x;
  int tr = t >> 3, tc = t & 7;
  const float* src = W_out + (long)l * 131072 + (long)(kt * 32) * 512 + nt * 32;
  float4 v = *(const float4*)(src + (long)tr * 512 + tc * 4);
  T[tr][tc * 4 + 0] = v.x; T[tr][tc * 4 + 1] = v.y;
  T[tr][tc * 4 + 2] = v.z; T[tr][tc * 4 + 3] = v.w;
  __syncthreads();
  ushort4 o;
  o.x = f2bf(T[tc * 4 + 0][tr]); o.y = f2bf(T[tc * 4 + 1][tr]);
  o.z = f2bf(T[tc * 4 + 2][tr]); o.w = f2bf(T[tc * 4 + 3][tr]);
  *(ushort4*)(g_Wt + ((long)l * 512 + nt * 32 + tr) * 256 + kt * 32 + tc * 4) = o;
}

// ---------- W_in [k=128][n=256] -> Wint bf16 [n][k] ----------
__global__ void k_prepWin(const float* __restrict__ W_in) {
  int k = blockIdx.x, n = threadIdx.x;
  g_Wint[n * 128 + k] = f2bf(W_in[k * 256 + n]);
}

// ---------- x_in fp32 -> bf16 ----------
__global__ void k_castin(const float* __restrict__ xin) {
  long base = ((long)blockIdx.x * 256 + threadIdx.x) * 8;
  float4 v0 = *(const float4*)(xin + base);
  float4 v1 = *(const float4*)(xin + base + 4);
  union { unsigned short u[8]; ulonglong2 v; } pk;
  pk.u[0] = f2bf(v0.x); pk.u[1] = f2bf(v0.y); pk.u[2] = f2bf(v0.z); pk.u[3] = f2bf(v0.w);
  pk.u[4] = f2bf(v1.x); pk.u[5] = f2bf(v1.y); pk.u[6] = f2bf(v1.z); pk.u[7] = f2bf(v1.w);
  *(ulonglong2*)(g_xb + base) = pk.v;
}

// ---------- input GEMM (bf16 MFMA): x[32768,256] = xb[32768,128]*Wint^T + b -> bf16 ----------
__global__ __launch_bounds__(256) void k_gemmin(const float* __restrict__ bias) {
  __shared__ __attribute__((aligned(16))) unsigned short As[128 * 32];
  __shared__ __attribute__((aligned(16))) unsigned short Bs[256 * 32];
  const int tid = threadIdx.x;
  const int wave = tid >> 6, lane = tid & 63;
  const int m0 = blockIdx.x * 128;
  const int wm = wave & 1, wn = wave >> 1;
  const int n15 = lane & 15, kg = lane >> 4, q2 = kg * 8;
  f32x4 acc[4][8];
  #pragma unroll
  for (int a = 0; a < 4; ++a)
    #pragma unroll
    for (int b2 = 0; b2 < 8; ++b2) acc[a][b2] = (f32x4){0.f, 0.f, 0.f, 0.f};
  for (int k0 = 0; k0 < 128; k0 += 32) {
    __syncthreads();
    #pragma unroll
    for (int it = 0; it < 2; ++it) {
      int slot = it * 256 + wave * 64 + lane;
      int m = slot >> 2, ko = (slot & 3) * 8;
      __builtin_amdgcn_global_load_lds(
        (const __attribute__((address_space(1))) unsigned int*)(g_xb + (long)(m0 + m) * 128 + k0 + ko),
        (__attribute__((address_space(3))) unsigned int*)(As + (it * 256 + wave * 64) * 8),
        16, 0, 0);
    }
    #pragma unroll
    for (int it = 0; it < 4; ++it) {
      int slot = it * 256 + wave * 64 + lane;
      int n = slot >> 2, ko = (slot & 3) * 8;
      __builtin_amdgcn_global_load_lds(
        (const __attribute__((address_space(1))) unsigned int*)(g_Wint + (long)n * 128 + k0 + ko),
        (__attribute__((address_space(3))) unsigned int*)(Bs + (it * 256 + wave * 64) * 8),
        16, 0, 0);
    }
    __syncthreads();
    bf16x8 af[4], bn[8];
    #pragma unroll
    for (int mt = 0; mt < 4; ++mt)
      af[mt] = *(const bf16x8*)&As[(wm * 64 + mt * 16 + n15) * 32 + q2];
    #pragma unroll
    for (int j = 0; j < 8; ++j)
      bn[j] = *(const bf16x8*)&Bs[(wn * 128 + j * 16 + n15) * 32 + q2];
    #pragma unroll
    for (int mt = 0; mt < 4; ++mt)
      #pragma unroll
      for (int j = 0; j < 8; ++j)
        acc[mt][j] = __builtin_amdgcn_mfma_f32_16x16x32_bf16(af[mt], bn[j], acc[mt][j], 0, 0, 0);
  }
  #pragma unroll
  for (int j = 0; j < 8; ++j) {
    int col = wn * 128 + j * 16 + n15;
    float bb = bias[col];
    #pragma unroll
    for (int mt = 0; mt < 4; ++mt)
      #pragma unroll
      for (int r = 0; r < 4; ++r) {
        int row = m0 + wm * 64 + mt * 16 + kg * 4 + r;
        g_xh[(long)row * 256 + col] = f2bf(acc[mt][j][r] + bb);
      }
  }
}

// ---------- LayerNorm over H -> z bf16 [B][H][L]; only for layer 0 ----------
__global__ __launch_bounds__(256) void k_ln(const float* __restrict__ gam,
                                            const float* __restrict__ bet) {
  __shared__ unsigned short S[32 * 264];
  const int bid = blockIdx.x;                  // 1024
  const int b = bid >> 6, l0 = (bid & 63) << 5;
  const int tid = threadIdx.x, w = tid >> 6, lane = tid & 63;
  float4 gv = *(const float4*)(gam + lane * 4);
  float4 bv = *(const float4*)(bet + lane * 4);
  for (int r = 0; r < 8; ++r) {
    int ll = w * 8 + r;
    ushort4 uv = *(const ushort4*)(g_xh + ((long)(b * LL + l0 + ll)) * HD + lane * 4);
    float vx = bf2f(uv.x), vy = bf2f(uv.y), vz = bf2f(uv.z), vw = bf2f(uv.w);
    float s1 = vx + vy + vz + vw;
    float s2 = vx * vx + vy * vy + vz * vz + vw * vw;
    #pragma unroll
    for (int off = 32; off; off >>= 1) { s1 += __shfl_xor(s1, off); s2 += __shfl_xor(s2, off); }
    float mu = s1 * (1.0f / HD);
    float rs = rsqrtf(s2 * (1.0f / HD) - mu * mu + 1e-5f);
    ushort4 o;
    o.x = f2bf((vx - mu) * rs * gv.x + bv.x);
    o.y = f2bf((vy - mu) * rs * gv.y + bv.y);
    o.z = f2bf((vz - mu) * rs * gv.z + bv.z);
    o.w = f2bf((vw - mu) * rs * gv.w + bv.w);
    *(ushort4*)&S[ll * 264 + lane * 4] = o;
  }
  __syncthreads();
  unsigned short* zp = g_zbh + ((long)(b * HD + tid)) * LL + l0;
  #pragma unroll
  for (int seg = 0; seg < 4; ++seg) {
    union { unsigned short u[8]; ulonglong2 v; } pk;
    #pragma unroll
    for (int i = 0; i < 8; ++i) pk.u[i] = S[(seg * 8 + i) * 264 + tid];
    *(ulonglong2*)(zp + seg * 8) = pk.v;
  }
}

// ---------- fused SSM: phaseA (MFMA) + chunk scan + phaseC (MFMA), one block per (b,h) ----------
__global__ __launch_bounds__(256) void k_ssm(int layer) {
  __shared__ __attribute__((aligned(16))) unsigned short Zs[32 * 72];   // z [c][t]
  __shared__ __attribute__((aligned(16))) unsigned short Ts[64 * 72];   // TA^T [p][t] | Ss fp32 [c][p] pitch 68
  __shared__ __attribute__((aligned(16))) unsigned short Ms[64 * 136];  // Mt [t][k]
  __shared__ __attribute__((aligned(16))) unsigned short Gs[32 * 72];   // G [c][p]
  float* Ss = (float*)Ts;
  const int tid = threadIdx.x, wave = tid >> 6, lane = tid & 63;
  const int h = blockIdx.x & 255, b = blockIdx.x >> 8;
  const long lh = (long)layer * HD + h;
  {
    int c = tid >> 3, off = (tid & 7) * 8;
    *(ulonglong2*)&Zs[c * 72 + off] =
        *(const ulonglong2*)(g_zbh + ((long)(b * HD + h)) * LL + c * 64 + off);
  }
  const unsigned short* Tg = g_TAt + lh * 4096;
  #pragma unroll
  for (int i = 0; i < 2; ++i) {
    int seg = tid + i * 256;
    int row = seg >> 3, sc = (seg & 7) * 8;
    *(ulonglong2*)&Ts[row * 72 + sc] = *(const ulonglong2*)(Tg + row * 64 + sc);
  }
  const unsigned short* Mg = g_Mt + lh * 8192;
  #pragma unroll
  for (int i = 0; i < 4; ++i) {
    int seg = tid + i * 256;
    int row = seg >> 4, sc = (seg & 15) * 8;
    *(ulonglong2*)&Ms[row * 136 + sc] = *(const ulonglong2*)(Mg + row * 128 + sc);
  }
  __syncthreads();
  const int n15 = lane & 15, kg = lane >> 4;
  const int mt = wave & 1;
  const int jb = (wave >> 1) * 2;
  const int c = mt * 16 + n15;
  {
    bf16x8 a0 = *(const bf16x8*)&Zs[c * 72 + kg * 8];
    bf16x8 a1 = *(const bf16x8*)&Zs[c * 72 + 32 + kg * 8];
    bf16x8 tb0[2], tb1[2];
    #pragma unroll
    for (int jj = 0; jj < 2; ++jj) {
      int j = jb + jj;
      tb0[jj] = *(const bf16x8*)&Ts[(j * 16 + n15) * 72 + kg * 8];
      tb1[jj] = *(const bf16x8*)&Ts[(j * 16 + n15) * 72 + 32 + kg * 8];
    }
    f32x4 accA[2];
    #pragma unroll
    for (int jj = 0; jj < 2; ++jj) {
      accA[jj] = (f32x4){0.f, 0.f, 0.f, 0.f};
      accA[jj] = __builtin_amdgcn_mfma_f32_16x16x32_bf16(a0, tb0[jj], accA[jj], 0, 0, 0);
      accA[jj] = __builtin_amdgcn_mfma_f32_16x16x32_bf16(a1, tb1[jj], accA[jj], 0, 0, 0);
    }
    __syncthreads();                     // all Ts reads done; safe to alias as Ss
    #pragma unroll
    for (int jj = 0; jj < 2; ++jj) {
      int j = jb + jj;
      #pragma unroll
      for (int r = 0; r < 4; ++r)
        Ss[(mt * 16 + kg * 4 + r) * 68 + j * 16 + n15] = accA[jj][r];
    }
  }
  __syncthreads();
  if (wave == 0 && lane < 32) {
    int n = lane;
    long vb = (lh * NS + n) * 65;
    float wtr = g_Vt[vb * 2 + 128], wti = g_Vt[vb * 2 + 129];
    float e0r = g_E0[(lh * NS + n) * 2], e0i = g_E0[(lh * NS + n) * 2 + 1];
    float sr = 0.f, si = 0.f;
    for (int cc = 0; cc < CC; ++cc) {
      float er = Ss[cc * 68 + 2 * n], ei = Ss[cc * 68 + 2 * n + 1];
      Gs[cc * 72 + 2 * n]     = f2bf(e0r * sr - e0i * si);
      Gs[cc * 72 + 2 * n + 1] = f2bf(e0r * si + e0i * sr);
      float nr = er + wtr * sr - wti * si;
      si      = ei + wtr * si + wti * sr;
      sr = nr;
    }
  }
  __syncthreads();
  {
    bf16x8 a0 = *(const bf16x8*)&Zs[c * 72 + kg * 8];
    bf16x8 a1 = *(const bf16x8*)&Zs[c * 72 + 32 + kg * 8];
    bf16x8 a2 = *(const bf16x8*)&Gs[c * 72 + kg * 8];
    bf16x8 a3 = *(const bf16x8*)&Gs[c * 72 + 32 + kg * 8];
    unsigned short* yrow = g_ybh + ((long)(b * HD + h)) * LL;
    #pragma unroll
    for (int jj = 0; jj < 2; ++jj) {
      int j = jb + jj;
      const unsigned short* mrow = &Ms[(j * 16 + n15) * 136];
      bf16x8 b0 = *(const bf16x8*)&mrow[kg * 8];
      bf16x8 b1 = *(const bf16x8*)&mrow[32 + kg * 8];
      bf16x8 b2 = *(const bf16x8*)&mrow[64 + kg * 8];
      bf16x8 b3 = *(const bf16x8*)&mrow[96 + kg * 8];
      f32x4 acc = (f32x4){0.f, 0.f, 0.f, 0.f};
      acc = __builtin_amdgcn_mfma_f32_16x16x32_bf16(a0, b0, acc, 0, 0, 0);
      acc = __builtin_amdgcn_mfma_f32_16x16x32_bf16(a1, b1, acc, 0, 0, 0);
      acc = __builtin_amdgcn_mfma_f32_16x16x32_bf16(a2, b2, acc, 0, 0, 0);
      acc = __builtin_amdgcn_mfma_f32_16x16x32_bf16(a3, b3, acc, 0, 0, 0);
      #pragma unroll
      for (int r = 0; r < 4; ++r)
        yrow[(mt * 16 + kg * 4 + r) * 64 + j * 16 + n15] = f2bf(geluf(acc[r]));
    }
  }
}

// ---------- fused: GEMM(yT * W) + GLU + residual + next-layer LN -> z ----------
// 32 l-rows x 512 cols; Bs staged async + XCD swizzle; residual stream bf16 (fp32 math).
__global__ __launch_bounds__(256, 4) void k_gemmglu(int layer, const float* __restrict__ bias,
                                                    const float* __restrict__ gam,
                                                    const float* __restrict__ bet,
                                                    int writez) {
  __shared__ __attribute__((aligned(16))) unsigned short As[32 * 40];    // 2.5 KB [l][k]
  __shared__ __attribute__((aligned(16))) unsigned short BX[512 * 32];   // 32 KB: Bs | Xs(bf16)
  __shared__ float Rs1[32][4], Rs2[32][4], muS[32], rsS[32];
  unsigned short* Bs = BX;                       // [n=512][k=32]
  unsigned short* Xs = BX;                       // [col=256][rl] pitch 34
  const int tid = threadIdx.x, wave = tid >> 6, lane = tid & 63;
  const int n15 = lane & 15, kg = lane >> 4, q2 = kg * 8;
  const int ltile = ((blockIdx.x & 7) << 7) | (blockIdx.x >> 3);
  const int row0 = ltile * 32;
  const int b = row0 >> 11, l0 = row0 & 2047;
  const unsigned short* Wt = g_Wt + (long)layer * 131072;
  const unsigned short* ybase = g_ybh + (long)b * HD * LL + l0;
  const int hl = tid >> 3, sg = tid & 7;         // A-staging: h-row, l-seg
  f32x4 acc[2][8];
  #pragma unroll
  for (int a = 0; a < 2; ++a)
    #pragma unroll
    for (int b2 = 0; b2 < 8; ++b2) acc[a][b2] = (f32x4){0.f, 0.f, 0.f, 0.f};
  for (int k0 = 0; k0 < 256; k0 += 32) {
    __syncthreads();
    // A: ybh[b][k0+hl][l0+sg*4 ..+4] -> As[l][h] (transpose)
    ushort4 av = *(const ushort4*)(ybase + (long)(k0 + hl) * LL + sg * 4);
    As[(sg * 4 + 0) * 40 + hl] = av.x;
    As[(sg * 4 + 1) * 40 + hl] = av.y;
    As[(sg * 4 + 2) * 40 + hl] = av.z;
    As[(sg * 4 + 3) * 40 + hl] = av.w;
    // B: all 512 n-rows, 32 k (async direct-to-LDS)
    #pragma unroll
    for (int it = 0; it < 8; ++it) {
      int slot = it * 256 + wave * 64 + lane;    // n = slot>>2, ko = (slot&3)*8
      int n = slot >> 2, ko = (slot & 3) * 8;
      __builtin_amdgcn_global_load_lds(
        (const __attribute__((address_space(1))) unsigned int*)(Wt + (long)n * 256 + k0 + ko),
        (__attribute__((address_space(3))) unsigned int*)(Bs + (it * 256 + wave * 64) * 8),
        16, 0, 0);
    }
    __syncthreads();
    bf16x8 af0 = *(const bf16x8*)&As[n15 * 40 + q2];
    bf16x8 af1 = *(const bf16x8*)&As[(16 + n15) * 40 + q2];
    #pragma unroll
    for (int j = 0; j < 4; ++j) {
      int nc = wave * 64 + j * 16 + n15;
      bf16x8 ba = *(const bf16x8*)&Bs[nc * 32 + q2];
      acc[0][j] = __builtin_amdgcn_mfma_f32_16x16x32_bf16(af0, ba, acc[0][j], 0, 0, 0);
      acc[1][j] = __builtin_amdgcn_mfma_f32_16x16x32_bf16(af1, ba, acc[1][j], 0, 0, 0);
      bf16x8 bg = *(const bf16x8*)&Bs[(nc + 256) * 32 + q2];
      acc[0][4 + j] = __builtin_amdgcn_mfma_f32_16x16x32_bf16(af0, bg, acc[0][4 + j], 0, 0, 0);
      acc[1][4 + j] = __builtin_amdgcn_mfma_f32_16x16x32_bf16(af1, bg, acc[1][4 + j], 0, 0, 0);
    }
  }
  __syncthreads();                  // Bs dead; Xs may be written now
  // epilogue: GLU + residual (bf16 stream, fp32 math) + exact fp32 row sums
  float s1l[2][4], s2l[2][4];
  #pragma unroll
  for (int mt = 0; mt < 2; ++mt)
    #pragma unroll
    for (int r = 0; r < 4; ++r) { s1l[mt][r] = 0.f; s2l[mt][r] = 0.f; }
  #pragma unroll
  for (int j = 0; j < 4; ++j) {
    int col = wave * 64 + j * 16 + n15;
    float ba = bias[col], bg = bias[col + 256];
    #pragma unroll
    for (int mt = 0; mt < 2; ++mt) {
      #pragma unroll
      for (int r = 0; r < 4; ++r) {
        int rl = mt * 16 + kg * 4 + r;
        long xi = (long)(row0 + rl) * 256 + col;
        float a = acc[mt][j][r] + ba;
        float g = acc[mt][4 + j][r] + bg;
        float xn = bf2f(g_xh[xi]) + a * sigf(g);
        g_xh[xi] = f2bf(xn);
        if (writez) {
          Xs[col * 34 + rl] = f2bf(xn);
          s1l[mt][r] += xn; s2l[mt][r] += xn * xn;
        }
      }
    }
  }
  if (!writez) return;
  #pragma unroll
  for (int mt = 0; mt < 2; ++mt)
    #pragma unroll
    for (int r = 0; r < 4; ++r) {
      #pragma unroll
      for (int off = 1; off < 16; off <<= 1) {
        s1l[mt][r] += __shfl_xor(s1l[mt][r], off);
        s2l[mt][r] += __shfl_xor(s2l[mt][r], off);
      }
    }
  if (n15 == 0) {
    #pragma unroll
    for (int mt = 0; mt < 2; ++mt)
      #pragma unroll
      for (int r = 0; r < 4; ++r) {
        Rs1[mt * 16 + kg * 4 + r][wave] = s1l[mt][r];
        Rs2[mt * 16 + kg * 4 + r][wave] = s2l[mt][r];
      }
  }
  __syncthreads();
  if (tid < 32) {
    float s1 = Rs1[tid][0] + Rs1[tid][1] + Rs1[tid][2] + Rs1[tid][3];
    float s2 = Rs2[tid][0] + Rs2[tid][1] + Rs2[tid][2] + Rs2[tid][3];
    float mu = s1 * (1.0f / HD);
    float rs = rsqrtf(s2 * (1.0f / HD) - mu * mu + 1e-5f);
    muS[tid] = mu; rsS[tid] = rs;
  }
  __syncthreads();
  {
    int hh = tid;
    float gm = gam[hh], bt = bet[hh];
    const unsigned short* xrow = &Xs[hh * 34];
    union { unsigned short u[32]; ulonglong2 v4[4]; } pk;
    #pragma unroll
    for (int rl = 0; rl < 32; ++rl)
      pk.u[rl] = f2bf((bf2f(xrow[rl]) - muS[rl]) * rsS[rl] * gm + bt);
    unsigned short* zp = g_zbh + ((long)(b * HD + hh)) * LL + l0;
    #pragma unroll
    for (int q = 0; q < 4; ++q) *(ulonglong2*)(zp + q * 8) = pk.v4[q];
  }
}

// ---------- final LN + partial pool (bf16 x) ----------
__global__ __launch_bounds__(256) void k_lnpool(const float* __restrict__ gam,
                                                const float* __restrict__ bet) {
  __shared__ float red[4][256];
  const int bid = blockIdx.x;
  const int b = bid >> 4, s = bid & 15;
  const int tid = threadIdx.x, w = tid >> 6, lane = tid & 63;
  float4 gv = *(const float4*)(gam + lane * 4);
  float4 bv = *(const float4*)(bet + lane * 4);
  float a0 = 0, a1 = 0, a2 = 0, a3 = 0;
  for (int r = 0; r < 32; ++r) {
    int l = s * 128 + w * 32 + r;
    ushort4 uv = *(const ushort4*)(g_xh + ((long)b * LL + l) * HD + lane * 4);
    float vx = bf2f(uv.x), vy = bf2f(uv.y), vz = bf2f(uv.z), vw = bf2f(uv.w);
    float s1 = vx + vy + vz + vw;
    float s2 = vx * vx + vy * vy + vz * vz + vw * vw;
    #pragma unroll
    for (int off = 32; off; off >>= 1) { s1 += __shfl_xor(s1, off); s2 += __shfl_xor(s2, off); }
    float mu = s1 * (1.0f / HD);
    float rs = rsqrtf(s2 * (1.0f / HD) - mu * mu + 1e-5f);
    a0 += (vx - mu) * rs * gv.x + bv.x;
    a1 += (vy - mu) * rs * gv.y + bv.y;
    a2 += (vz - mu) * rs * gv.z + bv.z;
    a3 += (vw - mu) * rs * gv.w + bv.w;
  }
  red[w][lane * 4 + 0] = a0; red[w][lane * 4 + 1] = a1;
  red[w][lane * 4 + 2] = a2; red[w][lane * 4 + 3] = a3;
  __syncthreads();
  g_pp[(long)bid * HD + tid] = red[0][tid] + red[1][tid] + red[2][tid] + red[3][tid];
}

// ---------- classifier ----------
__global__ __launch_bounds__(256) void k_cls(const float* __restrict__ Wc,
                                             const float* __restrict__ bc,
                                             float* __restrict__ out) {
  __shared__ float pl[256];
  const int b = blockIdx.x, tid = threadIdx.x;
  float p = 0.f;
  #pragma unroll
  for (int s = 0; s < 16; ++s) p += g_pp[((long)b * 16 + s) * HD + tid];
  pl[tid] = p * (1.0f / LL);
  __syncthreads();
  if (tid < NCLS) {
    float acc = bc[tid];
    for (int h = 0; h < HD; ++h) acc += pl[h] * Wc[h * NCLS + tid];
    out[b * NCLS + tid] = acc;
  }
}

extern "C" void kernel_launch(void* const* d_in, const int* in_sizes, int n_in,
                              void* d_out, int out_size, void* d_ws, size_t ws_size,
                              hipStream_t stream) {
  (void)in_sizes; (void)n_in; (void)d_ws; (void)ws_size; (void)out_size;
  const float* x_in   = (const float*)d_in[0];
  const float* W_in   = (const float*)d_in[1];
  const float* b_in   = (const float*)d_in[2];
  const float* log_dt = (const float*)d_in[3];
  const float* A_re   = (const float*)d_in[4];
  const float* A_im   = (const float*)d_in[5];
  const float* B_re   = (const float*)d_in[6];
  const float* B_im   = (const float*)d_in[7];
  const float* C_re   = (const float*)d_in[8];
  const float* C_im   = (const float*)d_in[9];
  const float* Dd     = (const float*)d_in[10];
  const float* W_out  = (const float*)d_in[11];
  const float* b_out  = (const float*)d_in[12];
  const float* ln_s   = (const float*)d_in[13];
  const float* ln_b   = (const float*)d_in[14];
  const float* lnf_s  = (const float*)d_in[15];
  const float* lnf_b  = (const float*)d_in[16];
  const float* W_cls  = (const float*)d_in[17];
  const float* b_cl   = (const float*)d_in[18];
  float* out = (float*)d_out;

  k_precomp<<<192, 256, 0, stream>>>(log_dt, A_re, A_im, B_re, B_im, C_re, C_im);
  k_precompK<<<384, 256, 0, stream>>>();
  k_precompM<<<49152, 256, 0, stream>>>(Dd);
  k_precompA2<<<24576, 256, 0, stream>>>();
  k_prepW<<<768, 256, 0, stream>>>(W_out);
  k_prepWin<<<128, 256, 0, stream>>>(W_in);
  k_castin<<<2048, 256, 0, stream>>>(x_in);
  k_gemmin<<<256, 256, 0, stream>>>(b_in);
  k_ln<<<1024, 256, 0, stream>>>(ln_s, ln_b);           // layer-0 prenorm
  for (int i = 0; i < NLAYERS; ++i) {
    int nl = (i + 1 < NLAYERS) ? (i + 1) : 0;
    k_ssm<<<4096, 256, 0, stream>>>(i);
    k_gemmglu<<<1024, 256, 0, stream>>>(i, b_out + i * 2 * HD,
                                        ln_s + nl * HD, ln_b + nl * HD,
                                        (i + 1 < NLAYERS) ? 1 : 0);
  }
  k_lnpool<<<256, 256, 0, stream>>>(lnf_s, lnf_b);
  k_cls<<<16, 256, 0, stream>>>(W_cls, b_cl, out);
}